// Round 1
// baseline (444.367 us; speedup 1.0000x reference)
//
#include <hip/hip_runtime.h>

// HexConv2d: y[b,o,p] = mask(p) * (bias[o] + sum_{n,c} W[o,c,n]*x[b,c,p+off_n]*valid_n(p))
// Implicit GEMM, bf16 MFMA 16x16x32. Block = 4 waves = 256 o x 64 pixels, one batch.
// K-loop: 8 chunks of 32 input channels; LDS stages a 168-pixel halo window per chunk
// (serves all 7 taps). A (weights) pre-packed to fragment order by prep kernel -> L2.

typedef __attribute__((ext_vector_type(8))) short short8;
typedef __attribute__((ext_vector_type(4))) float floatx4;

#define HW     49
#define NPIX   2401
#define PTILE  64
#define NPT    38      // ceil(2401/64)
#define WIN    168     // halo window rows (win_start = P0-52 .. P0+115)
#define PITCH  40      // bf16 per LDS row (80 B) -> 20-bank row stride, 2-way only
#define ZROW   168     // dedicated zero row for wrap-invalid taps
#define LDSROWS 170

__device__ __forceinline__ unsigned short f2bf(float f) {
  unsigned u = __builtin_bit_cast(unsigned, f);
  u += 0x7fffu + ((u >> 16) & 1u);          // RNE
  return (unsigned short)(u >> 16);
}

__device__ __forceinline__ bool hexmask(int gp) {
  int h = gp / 49;
  int w = gp - h * 49;
  int s = h + w;
  return (s >= 24 && s <= 72);
}

// W[o,c,n] fp32 (o stride 1792, c stride 7, n stride 1) -> bf16 fragment order:
// frag f = ((n*8+kc)*16+ot): lane l holds 8 bf16, element j = W[ot*16+(l&15)][kc*32+(l>>4)*8+j][n]
__global__ void prep_w_kernel(const float* __restrict__ w, unsigned short* __restrict__ wp) {
  int t = blockIdx.x * 256 + threadIdx.x;   // 0..57343 (= 7*8*16*64)
  int l  = t & 63;
  int ot = (t >> 6) & 15;
  int kc = (t >> 10) & 7;
  int n  = t >> 13;                          // 0..6
  int o  = ot * 16 + (l & 15);
  int cb = kc * 32 + ((l >> 4) * 8);
  const float* src = w + (size_t)(o * 256 + cb) * 7 + n;
  short8 pk;
#pragma unroll
  for (int j = 0; j < 8; ++j) pk[j] = (short)f2bf(src[j * 7]);
  ((short8*)wp)[t] = pk;
}

__global__ __launch_bounds__(256)
void hexconv_kernel(const float* __restrict__ x,
                    const unsigned short* __restrict__ wp,
                    const float* __restrict__ bias,
                    float* __restrict__ out) {
  __shared__ unsigned short smem[LDSROWS * PITCH];   // 13.6 KB

  const int tid  = threadIdx.x;
  const int lane = tid & 63;
  const int wv   = tid >> 6;        // wave 0..3 -> o block wv*64
  const int col  = lane & 15;
  const int quad = lane >> 4;

  const int pt = blockIdx.x;        // pixel tile 0..37
  const int b  = blockIdx.y;        // batch
  const int P0 = pt * PTILE;
  const int win_start = P0 - 52;    // (P0-49) & ~3, P0 % 4 == 0

  // zero rows 168..169 (wrap-invalid reads land here)
  if (tid < PITCH * 2) smem[ZROW * PITCH + tid] = 0;

  // flattened tap offsets for DIRS {(0,0),(1,0),(0,1),(-1,1),(-1,0),(0,-1),(1,-1)}
  const int OFF[7] = {0, 49, 1, -48, -49, -1, 48};
  const int DXP = (1 << 2) | (1 << 3);   // taps with dx=+1: invalid at w==48
  const int DXN = (1 << 5) | (1 << 6);   // taps with dx=-1: invalid at w==0

  // Precompute B-frag LDS byte addresses per (pixel j-tile, tap)
  int baddr[4][7];
#pragma unroll
  for (int j = 0; j < 4; ++j) {
    int pix = P0 + j * 16 + col;
    int wj = pix % 49;
    int rowbase = pix - win_start;   // 52..115
#pragma unroll
    for (int n = 0; n < 7; ++n) {
      bool bad = (((DXP >> n) & 1) && wj == 48) || (((DXN >> n) & 1) && wj == 0);
      int row = bad ? ZROW : (rowbase + OFF[n]);   // 3..164 or ZROW
      baddr[j][n] = row * (PITCH * 2) + quad * 16;
    }
  }

  // Staging precompute: each lane covers rows {lane, lane+64, lane+128} (clip <168)
  int sp[3], sgp[3];
  bool sok[3];
#pragma unroll
  for (int pi = 0; pi < 3; ++pi) {
    int p = lane + pi * 64;
    int gp = win_start + p;
    sp[pi] = p;
    sgp[pi] = gp;
    sok[pi] = (p < WIN) && (gp >= 0) && (gp < NPIX) && hexmask(gp);
  }

  floatx4 acc[4][4];
#pragma unroll
  for (int i = 0; i < 4; ++i)
#pragma unroll
    for (int j = 0; j < 4; ++j) acc[i][j] = (floatx4){0.f, 0.f, 0.f, 0.f};

  const short8* wpv = (const short8*)wp;
  const int wslot = wv * 4;

  for (int kc = 0; kc < 8; ++kc) {
    __syncthreads();   // prior compute done reading LDS
    // ---- stage x[b, kc*32 .. kc*32+31, window] * hexmask -> LDS bf16 [pix][c] ----
#pragma unroll
    for (int ci = 0; ci < 8; ++ci) {
      int c = ci * 4 + wv;   // waves split channels -> coalesced pixel-contiguous loads
      const float* src = x + ((size_t)(b * 256 + kc * 32 + c)) * NPIX;
#pragma unroll
      for (int pi = 0; pi < 3; ++pi) {
        if (sp[pi] < WIN) {
          float v = sok[pi] ? src[sgp[pi]] : 0.f;
          smem[sp[pi] * PITCH + c] = f2bf(v);
        }
      }
    }
    __syncthreads();
    // ---- compute: 7 taps x 16 MFMAs ----
#pragma unroll
    for (int n = 0; n < 7; ++n) {
      short8 af[4];
#pragma unroll
      for (int i = 0; i < 4; ++i)
        af[i] = wpv[((size_t)((n * 8 + kc) * 16 + wslot + i)) * 64 + lane];
      short8 bf[4];
#pragma unroll
      for (int j = 0; j < 4; ++j)
        bf[j] = *(const short8*)((const char*)smem + baddr[j][n]);
#pragma unroll
      for (int i = 0; i < 4; ++i)
#pragma unroll
        for (int j = 0; j < 4; ++j)
          acc[i][j] = __builtin_amdgcn_mfma_f32_16x16x32_bf16(af[i], bf[j], acc[i][j], 0, 0, 0);
    }
  }

  // ---- epilogue: D[row=quad*4+r][col=lane&15]; o = wv*64+i*16+quad*4+r, pix = P0+j*16+col ----
  const int ob = wv * 64;
  floatx4 bv[4];
#pragma unroll
  for (int i = 0; i < 4; ++i)
    bv[i] = *(const floatx4*)(bias + ob + i * 16 + quad * 4);

#pragma unroll
  for (int j = 0; j < 4; ++j) {
    int pix = P0 + j * 16 + col;
    if (pix >= NPIX) continue;
    int h = pix / 49;
    int w = pix - h * 49;
    bool m = (h + w >= 24 && h + w <= 72);
#pragma unroll
    for (int i = 0; i < 4; ++i) {
      int o = ob + i * 16 + quad * 4;
      float* dst = out + ((size_t)(b * 256 + o)) * NPIX + pix;
#pragma unroll
      for (int r = 0; r < 4; ++r) {
        float v = m ? (acc[i][j][r] + bv[i][r]) : 0.f;
        dst[(size_t)r * NPIX] = v;
      }
    }
  }
}

extern "C" void kernel_launch(void* const* d_in, const int* in_sizes, int n_in,
                              void* d_out, int out_size, void* d_ws, size_t ws_size,
                              hipStream_t stream) {
  const float* x    = (const float*)d_in[0];   // [32,256,49,49]
  const float* w    = (const float*)d_in[1];   // [256,256,7]
  const float* bias = (const float*)d_in[2];   // [256]
  float* out = (float*)d_out;                  // [32,256,49,49]
  unsigned short* wp = (unsigned short*)d_ws;  // 917,504 B packed bf16 weights

  prep_w_kernel<<<224, 256, 0, stream>>>(w, wp);
  dim3 grid(NPT, 32);
  hexconv_kernel<<<grid, 256, 0, stream>>>(x, wp, bias, out);
}

// Round 2
// 286.702 us; speedup vs baseline: 1.5499x; 1.5499x over previous
//
#include <hip/hip_runtime.h>

// HexConv2d implicit GEMM, bf16 MFMA 16x16x32.
// v2: prep kernel pre-converts x -> pixel-major masked zero-padded bf16 (xb in ws);
// main kernel stages B via global_load_lds (16B) with XOR bank swizzle; A (weights)
// pre-packed to fragment order (wp in ws), read from global/L2.

typedef __attribute__((ext_vector_type(8))) short short8;
typedef __attribute__((ext_vector_type(4))) float floatx4;

#define NPIX   2401
#define PTILE  64
#define NPT    38        // ceil(2401/64)
#define NSEG   11        // 11 * 16 = 176 window rows (win_start = P0-52 .. P0+123)
#define WINROWS (NSEG*16)
#define ZROW   176
#define PADROWS 2560     // padded pixel rows per batch in xb
#define PADBASE 64       // xb row PADBASE == pixel 0
// ws layout: xb [32][2560][256] bf16 = 41,943,040 B ; wp 917,504 B
#define XB_BYTES 41943040ULL
#define WS_NEED  (XB_BYTES + 917504ULL)

__device__ __forceinline__ unsigned short f2bf(float f) {
  unsigned u = __builtin_bit_cast(unsigned, f);
  u += 0x7fffu + ((u >> 16) & 1u);          // RNE
  return (unsigned short)(u >> 16);
}

__device__ __forceinline__ bool hexmask(int gp) {
  int h = gp / 49;
  int w = gp - h * 49;
  int s = h + w;
  return (s >= 24 && s <= 72);
}

// ---------------- prep: W[o,c,n] fp32 -> bf16 MFMA-A fragment order ----------------
// frag f = ((n*8+kc)*16+ot): lane l holds 8 bf16: W[ot*16+(l&15)][kc*32+(l>>4)*8+j][n]
__global__ void prep_w_kernel(const float* __restrict__ w, unsigned short* __restrict__ wp) {
  int t = blockIdx.x * 256 + threadIdx.x;   // 0..57343
  int l  = t & 63;
  int ot = (t >> 6) & 15;
  int kc = (t >> 10) & 7;
  int n  = t >> 13;
  int o  = ot * 16 + (l & 15);
  int cb = kc * 32 + ((l >> 4) * 8);
  const float* src = w + (size_t)(o * 256 + cb) * 7 + n;
  short8 pk;
#pragma unroll
  for (int j = 0; j < 8; ++j) pk[j] = (short)f2bf(src[j * 7]);
  ((short8*)wp)[t] = pk;
}

// ---------------- prep: x [b][c][p] fp32 -> xb [b][row][c] bf16, masked + zero pads --
__global__ __launch_bounds__(256)
void prep_x_kernel(const float* __restrict__ x, unsigned short* __restrict__ xb) {
  __shared__ unsigned short t[64][72];      // [ch_local][pix_local], pitch 72
  const int b    = blockIdx.y;
  const int row0 = blockIdx.x * 64;          // padded row
  const int gp0  = row0 - PADBASE;           // pixel index of pix_local 0
  const int tid  = threadIdx.x;
  const int chl  = tid >> 2;
  const int pgrp = (tid & 3) * 16;
  const int pixw = tid >> 2;
  const int cgrp = (tid & 3) * 16;

  for (int ct = 0; ct < 4; ++ct) {
    int ch = ct * 64 + chl;
    const float* src = x + ((size_t)(b * 256 + ch)) * NPIX;
    unsigned short v[16];
#pragma unroll
    for (int j = 0; j < 16; ++j) {
      int gp = gp0 + pgrp + j;
      float f = (gp >= 0 && gp < NPIX && hexmask(gp)) ? src[gp] : 0.f;
      v[j] = f2bf(f);
    }
    __syncthreads();
#pragma unroll
    for (int j = 0; j < 16; ++j) t[chl][pgrp + j] = v[j];
    __syncthreads();
    short8 o0, o1;
#pragma unroll
    for (int j = 0; j < 8; ++j) o0[j] = (short)t[cgrp + j][pixw];
#pragma unroll
    for (int j = 0; j < 8; ++j) o1[j] = (short)t[cgrp + 8 + j][pixw];
    unsigned short* dst = xb + ((size_t)b * PADROWS + row0 + pixw) * 256 + ct * 64 + cgrp;
    *(short8*)dst = o0;
    *(short8*)(dst + 8) = o1;
  }
}

// ---------------- main: v2 with global_load_lds staging ----------------
__global__ __launch_bounds__(256)
void hexconv_v2(const unsigned short* __restrict__ xb,
                const unsigned short* __restrict__ wp,
                const float* __restrict__ bias,
                float* __restrict__ out) {
  __shared__ __attribute__((aligned(16))) unsigned char smem[(ZROW + 1) * 64];  // 11,328 B

  const int tid  = threadIdx.x;
  const int lane = tid & 63;
  const int wv   = tid >> 6;
  const int col  = lane & 15;
  const int quad = lane >> 4;

  const int pt = blockIdx.x;
  const int b  = blockIdx.y;
  const int P0 = pt * PTILE;
  const int win_start = P0 - 52;

  // zero row (wrap-invalid taps read here)
  if (tid < 16) ((unsigned*)smem)[ZROW * 16 + tid] = 0;

  const int OFF[7] = {0, 49, 1, -48, -49, -1, 48};
  const int DXP = (1 << 2) | (1 << 3);   // dx=+1 taps: invalid at w==48
  const int DXN = (1 << 5) | (1 << 6);   // dx=-1 taps: invalid at w==0

  // B-frag LDS byte addresses per (j-tile, tap), with XOR swizzle part = quad^((r>>1)&3)
  int baddr[4][7];
#pragma unroll
  for (int j = 0; j < 4; ++j) {
    int pix = P0 + j * 16 + col;
    int wj = pix % 49;
    int rowbase = j * 16 + col + 52;
#pragma unroll
    for (int n = 0; n < 7; ++n) {
      bool bad = (((DXP >> n) & 1) && wj == 48) || (((DXN >> n) & 1) && wj == 0);
      int r = rowbase + OFF[n];                       // 3..164
      int pp = (quad ^ ((r >> 1) & 3)) & 3;
      baddr[j][n] = bad ? (ZROW * 64 + quad * 16) : (r * 64 + pp * 16);
    }
  }

  // staging: per wave, segments s = wv, wv+4, wv+8 (<11); lane l covers row 16s+(l>>2),
  // LDS part l&3, global part (l&3)^((l>>3)&3)  (the swizzle, applied on global side)
  const int gpart = (lane & 3) ^ ((lane >> 3) & 3);
  const unsigned short* xbrow = xb + ((size_t)b * PADROWS + PADBASE + win_start) * 256;
  const char* gsrc0 = (const char*)xbrow + (lane >> 2) * 512 + gpart * 16;

  floatx4 acc[4][4];
#pragma unroll
  for (int i = 0; i < 4; ++i)
#pragma unroll
    for (int j = 0; j < 4; ++j) acc[i][j] = (floatx4){0.f, 0.f, 0.f, 0.f};

  const char* wbase = (const char*)wp + ((size_t)(wv * 4) * 64 + lane) * 16;

  for (int kc = 0; kc < 8; ++kc) {
    __syncthreads();   // prior compute done reading LDS
#pragma unroll
    for (int s = wv; s < NSEG; s += 4) {
      const char* g = gsrc0 + (size_t)s * (16 * 512) + kc * 64;
      __builtin_amdgcn_global_load_lds(
          (const __attribute__((address_space(1))) unsigned int*)g,
          (__attribute__((address_space(3))) unsigned int*)(smem + s * 1024),
          16, 0, 0);
    }
    __syncthreads();
#pragma unroll
    for (int n = 0; n < 7; ++n) {
      short8 af[4];
#pragma unroll
      for (int i = 0; i < 4; ++i)
        af[i] = *(const short8*)(wbase + ((size_t)((n * 8 + kc) * 16 + i)) * 1024);
      short8 bf[4];
#pragma unroll
      for (int j = 0; j < 4; ++j)
        bf[j] = *(const short8*)(smem + baddr[j][n]);
#pragma unroll
      for (int i = 0; i < 4; ++i)
#pragma unroll
        for (int j = 0; j < 4; ++j)
          acc[i][j] = __builtin_amdgcn_mfma_f32_16x16x32_bf16(af[i], bf[j], acc[i][j], 0, 0, 0);
    }
  }

  // epilogue: D[row=quad*4+r][col]; o = wv*64+i*16+quad*4+r, pix = P0+j*16+col
  const int ob = wv * 64;
  floatx4 bv[4];
#pragma unroll
  for (int i = 0; i < 4; ++i)
    bv[i] = *(const floatx4*)(bias + ob + i * 16 + quad * 4);

#pragma unroll
  for (int j = 0; j < 4; ++j) {
    int pix = P0 + j * 16 + col;
    if (pix >= NPIX) continue;
    int h = pix / 49;
    int w = pix - h * 49;
    bool m = (h + w >= 24 && h + w <= 72);
#pragma unroll
    for (int i = 0; i < 4; ++i) {
      int o = ob + i * 16 + quad * 4;
      float* dst = out + ((size_t)(b * 256 + o)) * NPIX + pix;
#pragma unroll
      for (int r = 0; r < 4; ++r) {
        float v = m ? (acc[i][j][r] + bv[i][r]) : 0.f;
        dst[(size_t)r * NPIX] = v;
      }
    }
  }
}

// ---------------- fallback v1 (used when ws too small for xb) ----------------
#define PITCH  40
#define V1WIN  168
#define V1ZROW 168
__global__ __launch_bounds__(256)
void hexconv_v1(const float* __restrict__ x,
                const unsigned short* __restrict__ wp,
                const float* __restrict__ bias,
                float* __restrict__ out) {
  __shared__ unsigned short sm[(V1ZROW + 2) * PITCH];
  const int tid = threadIdx.x, lane = tid & 63, wv = tid >> 6;
  const int col = lane & 15, quad = lane >> 4;
  const int pt = blockIdx.x, b = blockIdx.y;
  const int P0 = pt * PTILE, win_start = P0 - 52;
  if (tid < PITCH * 2) sm[V1ZROW * PITCH + tid] = 0;
  const int OFF[7] = {0, 49, 1, -48, -49, -1, 48};
  const int DXP = (1 << 2) | (1 << 3), DXN = (1 << 5) | (1 << 6);
  int baddr[4][7];
#pragma unroll
  for (int j = 0; j < 4; ++j) {
    int pix = P0 + j * 16 + col;
    int wj = pix % 49;
    int rowbase = pix - win_start;
#pragma unroll
    for (int n = 0; n < 7; ++n) {
      bool bad = (((DXP >> n) & 1) && wj == 48) || (((DXN >> n) & 1) && wj == 0);
      int row = bad ? V1ZROW : (rowbase + OFF[n]);
      baddr[j][n] = row * (PITCH * 2) + quad * 16;
    }
  }
  int sp[3], sgp[3]; bool sok[3];
#pragma unroll
  for (int pi = 0; pi < 3; ++pi) {
    int p = lane + pi * 64, gp = win_start + p;
    sp[pi] = p; sgp[pi] = gp;
    sok[pi] = (p < V1WIN) && (gp >= 0) && (gp < NPIX) && hexmask(gp);
  }
  floatx4 acc[4][4];
#pragma unroll
  for (int i = 0; i < 4; ++i)
#pragma unroll
    for (int j = 0; j < 4; ++j) acc[i][j] = (floatx4){0.f, 0.f, 0.f, 0.f};
  const short8* wpv = (const short8*)wp;
  const int wslot = wv * 4;
  for (int kc = 0; kc < 8; ++kc) {
    __syncthreads();
#pragma unroll
    for (int ci = 0; ci < 8; ++ci) {
      int c = ci * 4 + wv;
      const float* src = x + ((size_t)(b * 256 + kc * 32 + c)) * NPIX;
#pragma unroll
      for (int pi = 0; pi < 3; ++pi) {
        if (sp[pi] < V1WIN) {
          float v = sok[pi] ? src[sgp[pi]] : 0.f;
          sm[sp[pi] * PITCH + c] = f2bf(v);
        }
      }
    }
    __syncthreads();
#pragma unroll
    for (int n = 0; n < 7; ++n) {
      short8 af[4];
#pragma unroll
      for (int i = 0; i < 4; ++i)
        af[i] = wpv[((size_t)((n * 8 + kc) * 16 + wslot + i)) * 64 + lane];
      short8 bf[4];
#pragma unroll
      for (int j = 0; j < 4; ++j)
        bf[j] = *(const short8*)((const char*)sm + baddr[j][n]);
#pragma unroll
      for (int i = 0; i < 4; ++i)
#pragma unroll
        for (int j = 0; j < 4; ++j)
          acc[i][j] = __builtin_amdgcn_mfma_f32_16x16x32_bf16(af[i], bf[j], acc[i][j], 0, 0, 0);
    }
  }
  const int ob = wv * 64;
  floatx4 bv[4];
#pragma unroll
  for (int i = 0; i < 4; ++i)
    bv[i] = *(const floatx4*)(bias + ob + i * 16 + quad * 4);
#pragma unroll
  for (int j = 0; j < 4; ++j) {
    int pix = P0 + j * 16 + col;
    if (pix >= NPIX) continue;
    int h = pix / 49, w = pix - h * 49;
    bool m = (h + w >= 24 && h + w <= 72);
#pragma unroll
    for (int i = 0; i < 4; ++i) {
      int o = ob + i * 16 + quad * 4;
      float* dst = out + ((size_t)(b * 256 + o)) * NPIX + pix;
#pragma unroll
      for (int r = 0; r < 4; ++r) {
        float v = m ? (acc[i][j][r] + bv[i][r]) : 0.f;
        dst[(size_t)r * NPIX] = v;
      }
    }
  }
}

extern "C" void kernel_launch(void* const* d_in, const int* in_sizes, int n_in,
                              void* d_out, int out_size, void* d_ws, size_t ws_size,
                              hipStream_t stream) {
  const float* x    = (const float*)d_in[0];   // [32,256,49,49]
  const float* w    = (const float*)d_in[1];   // [256,256,7]
  const float* bias = (const float*)d_in[2];   // [256]
  float* out = (float*)d_out;

  if (ws_size >= WS_NEED) {
    unsigned short* xb = (unsigned short*)d_ws;
    unsigned short* wp = (unsigned short*)((char*)d_ws + XB_BYTES);
    prep_x_kernel<<<dim3(PADROWS / 64, 32), 256, 0, stream>>>(x, xb);
    prep_w_kernel<<<224, 256, 0, stream>>>(w, wp);
    hexconv_v2<<<dim3(NPT, 32), 256, 0, stream>>>(xb, wp, bias, out);
  } else {
    unsigned short* wp = (unsigned short*)d_ws;
    prep_w_kernel<<<224, 256, 0, stream>>>(w, wp);
    hexconv_v1<<<dim3(NPT, 32), 256, 0, stream>>>(x, wp, bias, out);
  }
}

// Round 3
// 238.985 us; speedup vs baseline: 1.8594x; 1.1997x over previous
//
#include <hip/hip_runtime.h>

// HexConv2d implicit GEMM, bf16 MFMA 16x16x32.
// v3: pitch-50 padded pixel space (wrap taps read natural zeros), 256o x 128pix
// blocks (acc 4x8/wave), double-buffered global_load_lds staging, one-tap-ahead
// A-fragment prefetch, kc-phase desync. Prep: coalesced transpose to pixel-major
// bf16 xb + pad-zero kernel + weight fragment packing.

typedef __attribute__((ext_vector_type(8))) short short8;
typedef __attribute__((ext_vector_type(4))) short short4v;
typedef __attribute__((ext_vector_type(4))) float floatx4;

#define NPIX   2401
#define W50    50
#define PREAL  2450      // 49 rows * 50
#define XBLEAD 56
#define XBROWS 2672      // [-56, 2616)
#define PT3    128       // pixels per block (padded space)
#define NT3    20        // 20*128 = 2560 >= 2450
#define NSEG3  15        // 240 window rows
#define BUFB   (NSEG3*1024)
#define XB3_BYTES ((size_t)32*XBROWS*256*2)   // 43,778,048
#define WP_BYTES  917504ULL
#define WS_NEED3  (XB3_BYTES + WP_BYTES)

__device__ __forceinline__ unsigned short f2bf(float f) {
  unsigned u = __builtin_bit_cast(unsigned, f);
  u += 0x7fffu + ((u >> 16) & 1u);          // RNE
  return (unsigned short)(u >> 16);
}

// ---------------- prep: W[o,c,n] fp32 -> bf16 MFMA-A fragment order ----------------
// frag f = ((n*8+kc)*16+ot): lane l holds 8 bf16: W[ot*16+(l&15)][kc*32+(l>>4)*8+j][n]
__global__ void prep_w_kernel(const float* __restrict__ w, unsigned short* __restrict__ wp) {
  int t = blockIdx.x * 256 + threadIdx.x;   // 0..57343
  int l  = t & 63;
  int ot = (t >> 6) & 15;
  int kc = (t >> 10) & 7;
  int n  = t >> 13;
  int o  = ot * 16 + (l & 15);
  int cb = kc * 32 + ((l >> 4) * 8);
  const float* src = w + (size_t)(o * 256 + cb) * 7 + n;
  short8 pk;
#pragma unroll
  for (int j = 0; j < 8; ++j) pk[j] = (short)f2bf(src[j * 7]);
  ((short8*)wp)[t] = pk;
}

// ---------------- prep: zero all pad rows of xb ----------------
__global__ void zero_pads(unsigned short* __restrict__ xb) {
  int idx = blockIdx.x * 256 + threadIdx.x;   // 32*2672*32 threads
  int c16 = idx & 31;
  int rb  = idx >> 5;
  int row = rb % XBROWS;
  int b   = rb / XBROWS;
  int p   = row - XBLEAD;
  bool pad = (p < 0) || (p >= PREAL) || (p % W50 == 49);
  if (pad) {
    short8 z = {0,0,0,0,0,0,0,0};
    *(short8*)(xb + ((size_t)b * XBROWS + row) * 256 + c16 * 8) = z;
  }
}

// ---------------- prep: x [b][c][2401] fp32 -> xb [b][row][256c] bf16 (masked) ------
__global__ __launch_bounds__(256)
void prep_x3(const float* __restrict__ x, unsigned short* __restrict__ xb) {
  __shared__ unsigned short t[64][68];
  const int tid = threadIdx.x;
  const int span = blockIdx.x, cg = blockIdx.y, b = blockIdx.z;
  const int s0 = span * 64;
  {
    const int chl = tid >> 2, i4 = tid & 3;
    const float* src = x + ((size_t)(b * 256 + cg * 64 + chl)) * NPIX;
#pragma unroll
    for (int it = 0; it < 4; ++it) {
      int pxl = it * 16 + i4 * 4;
      int r = s0 + pxl;
      float vv[4] = {0.f, 0.f, 0.f, 0.f};
      if (r + 3 < NPIX) {
        float4 v = *(const float4*)(src + r);
        vv[0] = v.x; vv[1] = v.y; vv[2] = v.z; vv[3] = v.w;
      } else {
#pragma unroll
        for (int e = 0; e < 4; ++e) if (r + e < NPIX) vv[e] = src[r + e];
      }
      short4v u = {0, 0, 0, 0};
#pragma unroll
      for (int e = 0; e < 4; ++e) {
        int re = r + e;
        unsigned short uu = 0;
        if (re < NPIX) {
          int h = re / 49, w = re - h * 49, s = h + w;
          if (s >= 24 && s <= 72) uu = f2bf(vv[e]);
        }
        u[e] = (short)uu;
      }
      *(short4v*)&t[chl][pxl] = u;
    }
  }
  __syncthreads();
  const int rl = tid >> 2, cpart = tid & 3;
  const int r = s0 + rl;
  if (r < NPIX) {
    int p = r + r / 49;                     // real -> padded index (h*50+w)
    unsigned short* dst = xb + ((size_t)b * XBROWS + (p + XBLEAD)) * 256 + cg * 64 + cpart * 16;
    short8 o0, o1;
#pragma unroll
    for (int k = 0; k < 8; ++k) o0[k] = (short)t[cpart * 16 + k][rl];
#pragma unroll
    for (int k = 0; k < 8; ++k) o1[k] = (short)t[cpart * 16 + 8 + k][rl];
    *(short8*)dst = o0;
    *(short8*)(dst + 8) = o1;
  }
}

// ---------------- main v3 ----------------
__global__ __launch_bounds__(256, 2)
void hexconv_v3(const unsigned short* __restrict__ xb,
                const unsigned short* __restrict__ wp,
                const float* __restrict__ bias,
                float* __restrict__ out) {
  __shared__ __attribute__((aligned(16))) unsigned char smem[2 * BUFB];  // 30720 B

  const int tid  = threadIdx.x;
  const int lane = tid & 63;
  const int wv   = tid >> 6;
  const int col  = lane & 15;
  const int quad = lane >> 4;

  const int pt = blockIdx.x;
  const int b  = blockIdx.y;
  const int P0 = pt * PT3;
  const int phase = (pt + b * 3) & 7;

  // tap offsets in pitch-50 padded space
  const int OFF[7] = {0, 50, 1, -49, -50, -1, 49};

  // B-frag LDS base addresses (kc- and j-invariant); XOR part swizzle folded in
  int ba[7];
#pragma unroll
  for (int n = 0; n < 7; ++n) {
    int r0 = col + 56 + OFF[n];              // 6..233
    int r64 = r0 << 6;
    ba[n] = (r64 + quad * 16) ^ ((r64 >> 3) & 0x30);
  }

  // staging source: lane l fetches row (16s + l>>2), global part (l&3)^((l>>3)&3)
  const int gpart = (lane & 3) ^ ((lane >> 3) & 3);
  const char* gsrc0 = (const char*)(xb + ((size_t)b * XBROWS + (size_t)P0) * 256)
                      + (lane >> 2) * 512 + gpart * 16;

  auto stage = [&](int buf, int kc) {
    char* ldsb = (char*)smem + buf * BUFB;
    for (int s = wv; s < NSEG3; s += 4)
      __builtin_amdgcn_global_load_lds(
          (const __attribute__((address_space(1))) unsigned int*)(gsrc0 + (size_t)s * 8192 + kc * 64),
          (__attribute__((address_space(3))) unsigned int*)(ldsb + s * 1024), 16, 0, 0);
  };

  const char* wbase = (const char*)wp + (size_t)(wv * 4) * 1024 + lane * 16;
  auto loadA = [&](int kc, int n, short8* dst) {
#pragma unroll
    for (int ii = 0; ii < 4; ++ii)
      dst[ii] = *(const short8*)(wbase + ((size_t)((n * 8 + kc) * 16 + ii)) * 1024);
  };

  floatx4 acc[4][8];
#pragma unroll
  for (int ii = 0; ii < 4; ++ii)
#pragma unroll
    for (int j = 0; j < 8; ++j) acc[ii][j] = (floatx4){0.f, 0.f, 0.f, 0.f};

  stage(0, phase);
  short8 afc[4];
  loadA(phase, 0, afc);
  __syncthreads();

  for (int i = 0; i < 8; ++i) {
    const int kc  = (i + phase) & 7;
    const int kcn = (i + 1 + phase) & 7;
    if (i < 7) stage((i + 1) & 1, kcn);
    const char* bufp = (const char*)smem + (i & 1) * BUFB;
#pragma unroll
    for (int n = 0; n < 7; ++n) {
      short8 afn[4];
      loadA((n < 6) ? kc : kcn, (n < 6) ? n + 1 : 0, afn);
      short8 bf[8];
#pragma unroll
      for (int j = 0; j < 8; ++j)
        bf[j] = *(const short8*)(bufp + ba[n] + j * 1024);
#pragma unroll
      for (int ii = 0; ii < 4; ++ii)
#pragma unroll
        for (int j = 0; j < 8; ++j)
          acc[ii][j] = __builtin_amdgcn_mfma_f32_16x16x32_bf16(afc[ii], bf[j], acc[ii][j], 0, 0, 0);
#pragma unroll
      for (int ii = 0; ii < 4; ++ii) afc[ii] = afn[ii];
    }
    __syncthreads();
  }

  // epilogue: D[row=quad*4+rr][col]; o = wv*64+ii*16+quad*4+rr, padded pix = P0+j*16+col
  const int ob = wv * 64;
  floatx4 bv[4];
#pragma unroll
  for (int ii = 0; ii < 4; ++ii)
    bv[ii] = *(const floatx4*)(bias + ob + ii * 16 + quad * 4);

#pragma unroll
  for (int j = 0; j < 8; ++j) {
    int p = P0 + j * 16 + col;
    int h = p / W50;
    int w = p - h * W50;
    if (w >= 49 || p >= PREAL) continue;
    bool m = (h + w >= 24) && (h + w <= 72);
    size_t ridx = (size_t)h * 49 + w;
#pragma unroll
    for (int ii = 0; ii < 4; ++ii) {
      float* dst = out + ((size_t)(b * 256 + ob + ii * 16 + quad * 4)) * NPIX + ridx;
#pragma unroll
      for (int rr = 0; rr < 4; ++rr) {
        float v = m ? (acc[ii][j][rr] + bv[ii][rr]) : 0.f;
        dst[(size_t)rr * NPIX] = v;
      }
    }
  }
}

// ---------------- fallback v1 (ws too small) ----------------
#define PITCH  40
#define V1WIN  168
#define V1ZROW 168
__global__ __launch_bounds__(256)
void hexconv_v1(const float* __restrict__ x,
                const unsigned short* __restrict__ wp,
                const float* __restrict__ bias,
                float* __restrict__ out) {
  __shared__ unsigned short sm[(V1ZROW + 2) * PITCH];
  const int tid = threadIdx.x, lane = tid & 63, wv = tid >> 6;
  const int col = lane & 15, quad = lane >> 4;
  const int pt = blockIdx.x, b = blockIdx.y;
  const int P0 = pt * 64, win_start = P0 - 52;
  if (tid < PITCH * 2) sm[V1ZROW * PITCH + tid] = 0;
  const int OFF[7] = {0, 49, 1, -48, -49, -1, 48};
  const int DXP = (1 << 2) | (1 << 3), DXN = (1 << 5) | (1 << 6);
  int baddr[4][7];
#pragma unroll
  for (int j = 0; j < 4; ++j) {
    int pix = P0 + j * 16 + col;
    int wj = pix % 49;
    int rowbase = pix - win_start;
#pragma unroll
    for (int n = 0; n < 7; ++n) {
      bool bad = (((DXP >> n) & 1) && wj == 48) || (((DXN >> n) & 1) && wj == 0);
      int row = bad ? V1ZROW : (rowbase + OFF[n]);
      baddr[j][n] = row * (PITCH * 2) + quad * 16;
    }
  }
  int sp[3], sgp[3]; bool sok[3];
#pragma unroll
  for (int pi = 0; pi < 3; ++pi) {
    int p = lane + pi * 64, gp = win_start + p;
    sp[pi] = p; sgp[pi] = gp;
    bool hm = false;
    if (gp >= 0 && gp < NPIX) { int h = gp / 49, w = gp - h * 49, s = h + w; hm = (s >= 24 && s <= 72); }
    sok[pi] = (p < V1WIN) && hm;
  }
  floatx4 acc[4][4];
#pragma unroll
  for (int i = 0; i < 4; ++i)
#pragma unroll
    for (int j = 0; j < 4; ++j) acc[i][j] = (floatx4){0.f, 0.f, 0.f, 0.f};
  const short8* wpv = (const short8*)wp;
  const int wslot = wv * 4;
  for (int kc = 0; kc < 8; ++kc) {
    __syncthreads();
#pragma unroll
    for (int ci = 0; ci < 8; ++ci) {
      int c = ci * 4 + wv;
      const float* src = x + ((size_t)(b * 256 + kc * 32 + c)) * NPIX;
#pragma unroll
      for (int pi = 0; pi < 3; ++pi) {
        if (sp[pi] < V1WIN) {
          float v = sok[pi] ? src[sgp[pi]] : 0.f;
          sm[sp[pi] * PITCH + c] = f2bf(v);
        }
      }
    }
    __syncthreads();
#pragma unroll
    for (int n = 0; n < 7; ++n) {
      short8 af[4];
#pragma unroll
      for (int i = 0; i < 4; ++i)
        af[i] = wpv[((size_t)((n * 8 + kc) * 16 + wslot + i)) * 64 + lane];
      short8 bf[4];
#pragma unroll
      for (int j = 0; j < 4; ++j)
        bf[j] = *(const short8*)((const char*)sm + baddr[j][n]);
#pragma unroll
      for (int i = 0; i < 4; ++i)
#pragma unroll
        for (int j = 0; j < 4; ++j)
          acc[i][j] = __builtin_amdgcn_mfma_f32_16x16x32_bf16(af[i], bf[j], acc[i][j], 0, 0, 0);
    }
  }
  const int ob = wv * 64;
  floatx4 bv[4];
#pragma unroll
  for (int i = 0; i < 4; ++i)
    bv[i] = *(const floatx4*)(bias + ob + i * 16 + quad * 4);
#pragma unroll
  for (int j = 0; j < 4; ++j) {
    int pix = P0 + j * 16 + col;
    if (pix >= NPIX) continue;
    int h = pix / 49, w = pix - h * 49;
    bool m = (h + w >= 24 && h + w <= 72);
#pragma unroll
    for (int i = 0; i < 4; ++i) {
      int o = ob + i * 16 + quad * 4;
      float* dst = out + ((size_t)(b * 256 + o)) * NPIX + pix;
#pragma unroll
      for (int r = 0; r < 4; ++r) {
        float v = m ? (acc[i][j][r] + bv[i][r]) : 0.f;
        dst[(size_t)r * NPIX] = v;
      }
    }
  }
}

extern "C" void kernel_launch(void* const* d_in, const int* in_sizes, int n_in,
                              void* d_out, int out_size, void* d_ws, size_t ws_size,
                              hipStream_t stream) {
  const float* x    = (const float*)d_in[0];   // [32,256,49,49]
  const float* w    = (const float*)d_in[1];   // [256,256,7]
  const float* bias = (const float*)d_in[2];   // [256]
  float* out = (float*)d_out;

  if (ws_size >= WS_NEED3) {
    unsigned short* xb = (unsigned short*)d_ws;
    unsigned short* wp = (unsigned short*)((char*)d_ws + XB3_BYTES);
    zero_pads<<<(32 * XBROWS * 32) / 256, 256, 0, stream>>>(xb);
    prep_w_kernel<<<224, 256, 0, stream>>>(w, wp);
    prep_x3<<<dim3(38, 4, 32), 256, 0, stream>>>(x, xb);
    hexconv_v3<<<dim3(NT3, 32), 256, 0, stream>>>(xb, wp, bias, out);
  } else {
    unsigned short* wp = (unsigned short*)d_ws;
    prep_w_kernel<<<224, 256, 0, stream>>>(w, wp);
    hexconv_v1<<<dim3(38, 32), 256, 0, stream>>>(x, wp, bias, out);
  }
}